// Round 6
// baseline (246.071 us; speedup 1.0000x reference)
//
#include <hip/hip_runtime.h>

#define NMOL 128
#define ZMAX 90
#define BLOCK_E 256
#define GRID_E 2048
#define BLOCK_P 256

typedef float  fx4 __attribute__((ext_vector_type(4)));
typedef int    ix4 __attribute__((ext_vector_type(4)));

__device__ __forceinline__ float fast_exp2(float x) {
#if __has_builtin(__builtin_amdgcn_exp2f)
    return __builtin_amdgcn_exp2f(x);
#else
    return exp2f(x);
#endif
}
__device__ __forceinline__ float fast_log2(float x) {
#if __has_builtin(__builtin_amdgcn_logf)
    return __builtin_amdgcn_logf(x);   // v_log_f32 computes log2(x)
#else
    return log2f(x);
#endif
}
__device__ __forceinline__ float fast_rcp(float x) {
#if __has_builtin(__builtin_amdgcn_rcpf)
    return __builtin_amdgcn_rcpf(x);
#else
    return 1.0f / x;
#endif
}

// Pack per-atom data into one 16B record: {q, ns, Z | is_film<<16, mol}.
// Cuts per-edge random gathers 9 -> 2 (+1 table line). Also zero-inits d_out
// (harness re-poisons it with 0xAA before every timed launch).
__global__ void pack_atoms_kernel(const float* __restrict__ q,
                                  const int* __restrict__ Z,
                                  const float* __restrict__ ns,
                                  const int* __restrict__ idx_m,
                                  const int* __restrict__ is_film,
                                  float4* __restrict__ atoms,
                                  float* __restrict__ out, int nA) {
    int t = blockIdx.x * BLOCK_P + threadIdx.x;
    if (blockIdx.x == 0 && threadIdx.x < NMOL) out[threadIdx.x] = 0.0f;
    if (t < nA) {
        float4 a;
        a.x = q[t];
        a.y = ns[t];
        a.z = __int_as_float(Z[t] | (is_film[t] << 16));
        a.w = __int_as_float(idx_m[t]);
        atoms[t] = a;
    }
}

// Per-edge tail math once ai/aj/r0 are in registers.
__device__ __forceinline__ float pot_from(const float4& ai, const float4& aj,
                                          float r0, float d2) {
    constexpr float LOG2_CUT = 2.321928094887362f; // log2(5.0)
    const float qij = fabsf(ai.x * aj.x);
    const float n = fmaf(0.5f, aj.y, ai.y);              // ns_i + ns_j/2
    const float B = qij * fast_exp2((n - 1.0f) * fast_log2(r0)) * fast_rcp(n);
    const float dpow = fast_exp2(-0.5f * n * fast_log2(d2)); // d^-n without sqrt
    const float cpow = fast_exp2(-n * LOG2_CUT);             // 5^-n
    return (d2 <= 25.0f) ? B * (dpow - cpow) : 0.0f;
}

__device__ __forceinline__ int tbl_idx(const float4& ai, const float4& aj) {
    int zi = __float_as_int(ai.z);
    int zj = __float_as_int(aj.z);
    const int fi = zi >> 16, fj = zj >> 16;
    zi &= 0xFFFF; zj &= 0xFFFF;
    return ((fi * 2 + fj) * ZMAX + zi) * ZMAX + zj;
}

// Max-occupancy edge kernel. Model from R2/R4 counters: random-gather
// throughput scales with resident waves (latency-bound, TLP-hidden), so we
// spend NO LDS on tables (bins only, 512B) and force VGPR<=64 via
// __launch_bounds__(256,8) -> up to 32 waves/CU vs 12 in the LDS-table build.
__global__ void __launch_bounds__(BLOCK_E, 8)
edge_kernel(const float4* __restrict__ atoms,
            const float* __restrict__ r0_table,
            const fx4* __restrict__ Rij4,
            const ix4* __restrict__ idx_i4,
            const ix4* __restrict__ idx_j4,
            float* __restrict__ out, int nE) {
    constexpr float HALF_KE = 7.1998f; // 0.5 * 14.3996

    __shared__ float bins[NMOL];
    for (int t = threadIdx.x; t < NMOL; t += BLOCK_E) bins[t] = 0.0f;
    __syncthreads();

    const int nE4 = nE >> 2;
    const int stride = gridDim.x * BLOCK_E;
    for (int t = blockIdx.x * BLOCK_E + threadIdx.x; t < nE4; t += stride) {
        // Streaming loads (nontemporal: don't pollute caches needed by gathers).
        const ix4 ii = __builtin_nontemporal_load(&idx_i4[t]);
        const ix4 jj = __builtin_nontemporal_load(&idx_j4[t]);
        const fx4 ra = __builtin_nontemporal_load(&Rij4[3 * t + 0]);
        const fx4 rb = __builtin_nontemporal_load(&Rij4[3 * t + 1]);
        const fx4 rc = __builtin_nontemporal_load(&Rij4[3 * t + 2]);

        // Issue all 8 atom gathers back-to-back.
        const float4 a0 = atoms[ii.x];
        const float4 a1 = atoms[ii.y];
        const float4 a2 = atoms[ii.z];
        const float4 a3 = atoms[ii.w];
        const float4 b0 = atoms[jj.x];
        const float4 b1 = atoms[jj.y];
        const float4 b2 = atoms[jj.z];
        const float4 b3 = atoms[jj.w];

        const float d20 = fmaf(ra.x, ra.x, fmaf(ra.y, ra.y, ra.z * ra.z));
        const float d21 = fmaf(ra.w, ra.w, fmaf(rb.x, rb.x, rb.y * rb.y));
        const float d22 = fmaf(rb.z, rb.z, fmaf(rb.w, rb.w, rc.x * rc.x));
        const float d23 = fmaf(rc.y, rc.y, fmaf(rc.z, rc.z, rc.w * rc.w));

        // Table lookups (130KB, L1/L2-cached; hottest lines stay in L1).
        const float r00 = r0_table[tbl_idx(a0, b0)];
        const float r01 = r0_table[tbl_idx(a1, b1)];
        const float r02 = r0_table[tbl_idx(a2, b2)];
        const float r03 = r0_table[tbl_idx(a3, b3)];

        const float p0 = pot_from(a0, b0, r00, d20);
        const float p1 = pot_from(a1, b1, r01, d21);
        const float p2 = pot_from(a2, b2, r02, d22);
        const float p3 = pot_from(a3, b3, r03, d23);

        if (p0 != 0.0f) atomicAdd(&bins[__float_as_int(a0.w)], p0);
        if (p1 != 0.0f) atomicAdd(&bins[__float_as_int(a1.w)], p1);
        if (p2 != 0.0f) atomicAdd(&bins[__float_as_int(a2.w)], p2);
        if (p3 != 0.0f) atomicAdd(&bins[__float_as_int(a3.w)], p3);
    }

    // Scalar tail for nE % 4 (empty for the canonical 6.4M edges).
    const int tail_start = nE4 << 2;
    const int* idx_i = (const int*)idx_i4;
    const int* idx_j = (const int*)idx_j4;
    const float* Rij = (const float*)Rij4;
    for (int e = tail_start + blockIdx.x * BLOCK_E + threadIdx.x; e < nE; e += stride) {
        const float4 ai = atoms[idx_i[e]];
        const float4 aj = atoms[idx_j[e]];
        const float x = Rij[3 * e + 0], y = Rij[3 * e + 1], z = Rij[3 * e + 2];
        const float d2 = fmaf(x, x, fmaf(y, y, z * z));
        const float p = pot_from(ai, aj, r0_table[tbl_idx(ai, aj)], d2);
        if (p != 0.0f) atomicAdd(&bins[__float_as_int(ai.w)], p);
    }

    __syncthreads();
    for (int t = threadIdx.x; t < NMOL; t += BLOCK_E) {
        const float v = bins[t];
        if (v != 0.0f) atomicAdd(&out[t], v * HALF_KE);
    }
}

// Fallback when d_ws can't hold packed atoms: raw gathers (slower, correct).
__global__ void __launch_bounds__(BLOCK_P)
edge_kernel_raw(const float* __restrict__ q,
                const int* __restrict__ Z,
                const float* __restrict__ ns,
                const int* __restrict__ idx_m,
                const int* __restrict__ is_film,
                const float* __restrict__ r0_table,
                const float* __restrict__ Rij,
                const int* __restrict__ idx_i,
                const int* __restrict__ idx_j,
                float* __restrict__ out, int nE) {
    constexpr float HALF_KE = 7.1998f;
    constexpr float LOG2_CUT = 2.321928094887362f;

    __shared__ float bins[NMOL];
    for (int t = threadIdx.x; t < NMOL; t += BLOCK_P) bins[t] = 0.0f;
    __syncthreads();

    const int stride = gridDim.x * BLOCK_P;
    for (int e = blockIdx.x * BLOCK_P + threadIdx.x; e < nE; e += stride) {
        const int i = idx_i[e];
        const int j = idx_j[e];
        const float x = Rij[3 * e + 0], y = Rij[3 * e + 1], z = Rij[3 * e + 2];
        const float d2 = fmaf(x, x, fmaf(y, y, z * z));
        const float r0 = r0_table[((is_film[i] * 2 + is_film[j]) * ZMAX + Z[i]) * ZMAX + Z[j]];
        const float qij = fabsf(q[i] * q[j]);
        const float n = fmaf(0.5f, ns[j], ns[i]);
        const float B = qij * fast_exp2((n - 1.0f) * fast_log2(r0)) * fast_rcp(n);
        const float dpow = fast_exp2(-0.5f * n * fast_log2(d2));
        const float cpow = fast_exp2(-n * LOG2_CUT);
        if (d2 <= 25.0f) atomicAdd(&bins[idx_m[i]], B * (dpow - cpow));
    }

    __syncthreads();
    for (int t = threadIdx.x; t < NMOL; t += BLOCK_P) {
        const float v = bins[t];
        if (v != 0.0f) atomicAdd(&out[t], v * HALF_KE);
    }
}

__global__ void zero_out_kernel(float* __restrict__ out) {
    if (threadIdx.x < NMOL) out[threadIdx.x] = 0.0f;
}

extern "C" void kernel_launch(void* const* d_in, const int* in_sizes, int n_in,
                              void* d_out, int out_size, void* d_ws, size_t ws_size,
                              hipStream_t stream) {
    const float* q        = (const float*)d_in[0];
    const int*   Z        = (const int*)  d_in[1];
    const float* ns       = (const float*)d_in[2];
    const int*   idx_m    = (const int*)  d_in[3];
    const float* Rij      = (const float*)d_in[4];
    const int*   idx_i    = (const int*)  d_in[5];
    const int*   idx_j    = (const int*)  d_in[6];
    const int*   is_film  = (const int*)  d_in[7];
    const float* r0_table = (const float*)d_in[8];

    const int nA = in_sizes[0];
    const int nE = in_sizes[5];
    float* out = (float*)d_out;

    const size_t atoms_bytes = (size_t)nA * sizeof(float4);

    if (ws_size >= atoms_bytes) {
        float4* atoms = (float4*)d_ws;
        const int pack_grid = (nA + BLOCK_P - 1) / BLOCK_P;
        pack_atoms_kernel<<<pack_grid, BLOCK_P, 0, stream>>>(q, Z, ns, idx_m, is_film,
                                                             atoms, out, nA);
        edge_kernel<<<GRID_E, BLOCK_E, 0, stream>>>(atoms, r0_table,
                                                    (const fx4*)Rij,
                                                    (const ix4*)idx_i,
                                                    (const ix4*)idx_j,
                                                    out, nE);
    } else {
        zero_out_kernel<<<1, BLOCK_P, 0, stream>>>(out);
        edge_kernel_raw<<<2048, BLOCK_P, 0, stream>>>(q, Z, ns, idx_m, is_film, r0_table,
                                                      Rij, idx_i, idx_j, out, nE);
    }
}

// Round 8
// 236.282 us; speedup vs baseline: 1.0414x; 1.0414x over previous
//
#include <hip/hip_runtime.h>

#define NMOL 128
#define ZMAX 90
#define TBL (2 * 2 * ZMAX * ZMAX)   // 32400 entries
#define BLOCK_E 1024
#define GRID_E 512                   // 2 blocks/CU exactly
#define BLOCK_P 256

typedef float  fx4 __attribute__((ext_vector_type(4)));
typedef int    ix4 __attribute__((ext_vector_type(4)));

__device__ __forceinline__ float fast_exp2(float x) {
#if __has_builtin(__builtin_amdgcn_exp2f)
    return __builtin_amdgcn_exp2f(x);
#else
    return exp2f(x);
#endif
}
__device__ __forceinline__ float fast_log2(float x) {
#if __has_builtin(__builtin_amdgcn_logf)
    return __builtin_amdgcn_logf(x);   // v_log_f32 computes log2(x)
#else
    return log2f(x);
#endif
}
__device__ __forceinline__ float fast_rcp(float x) {
#if __has_builtin(__builtin_amdgcn_rcpf)
    return __builtin_amdgcn_rcpf(x);
#else
    return 1.0f / x;
#endif
}

// Pack per-atom data into one 16B record: {q, ns, Z | is_film<<16, mol}.
// Also zero-inits d_out (harness re-poisons with 0xAA before every launch).
__global__ void pack_atoms_kernel(const float* __restrict__ q,
                                  const int* __restrict__ Z,
                                  const float* __restrict__ ns,
                                  const int* __restrict__ idx_m,
                                  const int* __restrict__ is_film,
                                  float4* __restrict__ atoms,
                                  float* __restrict__ out, int nA) {
    int t = blockIdx.x * BLOCK_P + threadIdx.x;
    if (blockIdx.x == 0 && threadIdx.x < NMOL) out[threadIdx.x] = 0.0f;
    if (t < nA) {
        float4 a;
        a.x = q[t];
        a.y = ns[t];
        a.z = __int_as_float(Z[t] | (is_film[t] << 16));
        a.w = __int_as_float(idx_m[t]);
        atoms[t] = a;
    }
}

// Quantize log2(r0_table) to i16 (x * 32768): abs err 2^-16 -> <=0.01% rel
// error in r0^(n-1) after *(n-1)<=10. 64.8KB -> fits LDS at 2 blocks/CU.
__global__ void build_tbl_kernel(const float* __restrict__ r0_table,
                                 short* __restrict__ tbl_q, int n) {
    int t = blockIdx.x * blockDim.x + threadIdx.x;
    if (t < n) {
        float v = log2f(r0_table[t]) * 32768.0f;
        int iv = (int)lrintf(v);
        iv = min(32767, max(-32768, iv));
        tbl_q[t] = (short)iv;
    }
}

__device__ __forceinline__ int tbl_idx(const float4& ai, const float4& aj) {
    int zi = __float_as_int(ai.z);
    int zj = __float_as_int(aj.z);
    const int fi = zi >> 16, fj = zj >> 16;
    zi &= 0xFFFF; zj &= 0xFFFF;
    return ((fi * 2 + fj) * ZMAX + zi) * ZMAX + zj;
}

// potential = (qij/n) * [exp2((n-1)t - 0.5 n log2 d2) - exp2((n-1)t - n log2 5)]
// where t = log2(r0). Two exp2 instead of three.
__device__ __forceinline__ float pot_from(const float4& ai, const float4& aj,
                                          float t, float d2) {
    constexpr float LOG2_CUT = 2.321928094887362f; // log2(5.0)
    const float qij = fabsf(ai.x * aj.x);
    const float n = fmaf(0.5f, aj.y, ai.y);          // ns_i + ns_j/2
    const float bexp = (n - 1.0f) * t;
    const float e1 = fmaf(-0.5f * n, fast_log2(d2), bexp);
    const float e2 = fmaf(-n, LOG2_CUT, bexp);
    const float p = qij * fast_rcp(n) * (fast_exp2(e1) - fast_exp2(e2));
    return (d2 <= 25.0f) ? p : 0.0f;
}

// Model (R2/R4/R6 counters): throughput wall = random L1-miss lines at
// ~0.29 lines/cy/CU (64-entry miss queue x ~220cy L2 latency). So: minimize
// random lines/edge (table -> LDS, 2 not 3) AND keep enough waves resident
// to fill the queue (i16 table = 64.8KB -> 2x1024-thread blocks/CU = 32 waves,
// vs 16 max for the f32 table).
__global__ void __launch_bounds__(BLOCK_E, 8)
edge_kernel(const float4* __restrict__ atoms,
            const short* __restrict__ tbl_q,
            const fx4* __restrict__ Rij4,
            const ix4* __restrict__ idx_i4,
            const ix4* __restrict__ idx_j4,
            float* __restrict__ out, int nE) {
    constexpr float HALF_KE = 7.1998f;      // 0.5 * 14.3996
    constexpr float ISCALE = 3.0517578125e-05f; // 2^-15

    __shared__ short r0l[TBL];   // 64800 B
    __shared__ float bins[NMOL];

    // Stage quantized table: 64800 B = 4050 x int4, exactly divisible.
    {
        const ix4* src = (const ix4*)tbl_q;
        ix4* dst = (ix4*)r0l;
        for (int t = threadIdx.x; t < TBL * 2 / 16; t += BLOCK_E) dst[t] = src[t];
    }
    for (int t = threadIdx.x; t < NMOL; t += BLOCK_E) bins[t] = 0.0f;
    __syncthreads();

    const int nE4 = nE >> 2;
    const int stride = gridDim.x * BLOCK_E;
    for (int t = blockIdx.x * BLOCK_E + threadIdx.x; t < nE4; t += stride) {
        const ix4 ii = __builtin_nontemporal_load(&idx_i4[t]);
        const ix4 jj = __builtin_nontemporal_load(&idx_j4[t]);
        const fx4 ra = __builtin_nontemporal_load(&Rij4[3 * t + 0]);
        const fx4 rb = __builtin_nontemporal_load(&Rij4[3 * t + 1]);
        const fx4 rc = __builtin_nontemporal_load(&Rij4[3 * t + 2]);

        // All 8 random gathers in flight together (fill the miss queue).
        const float4 a0 = atoms[ii.x];
        const float4 a1 = atoms[ii.y];
        const float4 a2 = atoms[ii.z];
        const float4 a3 = atoms[ii.w];
        const float4 b0 = atoms[jj.x];
        const float4 b1 = atoms[jj.y];
        const float4 b2 = atoms[jj.z];
        const float4 b3 = atoms[jj.w];

        const float d20 = fmaf(ra.x, ra.x, fmaf(ra.y, ra.y, ra.z * ra.z));
        const float d21 = fmaf(ra.w, ra.w, fmaf(rb.x, rb.x, rb.y * rb.y));
        const float d22 = fmaf(rb.z, rb.z, fmaf(rb.w, rb.w, rc.x * rc.x));
        const float d23 = fmaf(rc.y, rc.y, fmaf(rc.z, rc.z, rc.w * rc.w));

        // Table from LDS (no L2 request, separate pipe).
        const float t0 = (float)r0l[tbl_idx(a0, b0)] * ISCALE;
        const float t1 = (float)r0l[tbl_idx(a1, b1)] * ISCALE;
        const float t2 = (float)r0l[tbl_idx(a2, b2)] * ISCALE;
        const float t3 = (float)r0l[tbl_idx(a3, b3)] * ISCALE;

        const float p0 = pot_from(a0, b0, t0, d20);
        const float p1 = pot_from(a1, b1, t1, d21);
        const float p2 = pot_from(a2, b2, t2, d22);
        const float p3 = pot_from(a3, b3, t3, d23);

        if (p0 != 0.0f) atomicAdd(&bins[__float_as_int(a0.w)], p0);
        if (p1 != 0.0f) atomicAdd(&bins[__float_as_int(a1.w)], p1);
        if (p2 != 0.0f) atomicAdd(&bins[__float_as_int(a2.w)], p2);
        if (p3 != 0.0f) atomicAdd(&bins[__float_as_int(a3.w)], p3);
    }

    // Scalar tail for nE % 4 (empty at the canonical 6.4M edges).
    const int tail_start = nE4 << 2;
    const int* idx_i = (const int*)idx_i4;
    const int* idx_j = (const int*)idx_j4;
    const float* Rij = (const float*)Rij4;
    for (int e = tail_start + blockIdx.x * BLOCK_E + threadIdx.x; e < nE; e += stride) {
        const float4 ai = atoms[idx_i[e]];
        const float4 aj = atoms[idx_j[e]];
        const float x = Rij[3 * e + 0], y = Rij[3 * e + 1], z = Rij[3 * e + 2];
        const float d2 = fmaf(x, x, fmaf(y, y, z * z));
        const float tt = (float)r0l[tbl_idx(ai, aj)] * ISCALE;
        const float p = pot_from(ai, aj, tt, d2);
        if (p != 0.0f) atomicAdd(&bins[__float_as_int(ai.w)], p);
    }

    __syncthreads();
    for (int t = threadIdx.x; t < NMOL; t += BLOCK_E) {
        const float v = bins[t];
        if (v != 0.0f) atomicAdd(&out[t], v * HALF_KE);
    }
}

// Fallback when d_ws is too small: raw gathers (slower, correct).
__global__ void __launch_bounds__(BLOCK_P)
edge_kernel_raw(const float* __restrict__ q,
                const int* __restrict__ Z,
                const float* __restrict__ ns,
                const int* __restrict__ idx_m,
                const int* __restrict__ is_film,
                const float* __restrict__ r0_table,
                const float* __restrict__ Rij,
                const int* __restrict__ idx_i,
                const int* __restrict__ idx_j,
                float* __restrict__ out, int nE) {
    constexpr float HALF_KE = 7.1998f;
    constexpr float LOG2_CUT = 2.321928094887362f;

    __shared__ float bins[NMOL];
    for (int t = threadIdx.x; t < NMOL; t += BLOCK_P) bins[t] = 0.0f;
    __syncthreads();

    const int stride = gridDim.x * BLOCK_P;
    for (int e = blockIdx.x * BLOCK_P + threadIdx.x; e < nE; e += stride) {
        const int i = idx_i[e];
        const int j = idx_j[e];
        const float x = Rij[3 * e + 0], y = Rij[3 * e + 1], z = Rij[3 * e + 2];
        const float d2 = fmaf(x, x, fmaf(y, y, z * z));
        const float r0 = r0_table[((is_film[i] * 2 + is_film[j]) * ZMAX + Z[i]) * ZMAX + Z[j]];
        const float qij = fabsf(q[i] * q[j]);
        const float n = fmaf(0.5f, ns[j], ns[i]);
        const float B = qij * fast_exp2((n - 1.0f) * fast_log2(r0)) * fast_rcp(n);
        const float dpow = fast_exp2(-0.5f * n * fast_log2(d2));
        const float cpow = fast_exp2(-n * LOG2_CUT);
        if (d2 <= 25.0f) atomicAdd(&bins[idx_m[i]], B * (dpow - cpow));
    }

    __syncthreads();
    for (int t = threadIdx.x; t < NMOL; t += BLOCK_P) {
        const float v = bins[t];
        if (v != 0.0f) atomicAdd(&out[t], v * HALF_KE);
    }
}

__global__ void zero_out_kernel(float* __restrict__ out) {
    if (threadIdx.x < NMOL) out[threadIdx.x] = 0.0f;
}

extern "C" void kernel_launch(void* const* d_in, const int* in_sizes, int n_in,
                              void* d_out, int out_size, void* d_ws, size_t ws_size,
                              hipStream_t stream) {
    const float* q        = (const float*)d_in[0];
    const int*   Z        = (const int*)  d_in[1];
    const float* ns       = (const float*)d_in[2];
    const int*   idx_m    = (const int*)  d_in[3];
    const float* Rij      = (const float*)d_in[4];
    const int*   idx_i    = (const int*)  d_in[5];
    const int*   idx_j    = (const int*)  d_in[6];
    const int*   is_film  = (const int*)  d_in[7];
    const float* r0_table = (const float*)d_in[8];

    const int nA = in_sizes[0];
    const int nE = in_sizes[5];
    float* out = (float*)d_out;

    const size_t atoms_bytes = (size_t)nA * sizeof(float4); // 16B-aligned
    const size_t tbl_bytes = (size_t)TBL * sizeof(short);

    if (ws_size >= atoms_bytes + tbl_bytes) {
        float4* atoms = (float4*)d_ws;
        short* tbl_q = (short*)((char*)d_ws + atoms_bytes);
        const int pack_grid = (nA + BLOCK_P - 1) / BLOCK_P;
        pack_atoms_kernel<<<pack_grid, BLOCK_P, 0, stream>>>(q, Z, ns, idx_m, is_film,
                                                             atoms, out, nA);
        build_tbl_kernel<<<(TBL + 255) / 256, 256, 0, stream>>>(r0_table, tbl_q, TBL);
        edge_kernel<<<GRID_E, BLOCK_E, 0, stream>>>(atoms, tbl_q,
                                                    (const fx4*)Rij,
                                                    (const ix4*)idx_i,
                                                    (const ix4*)idx_j,
                                                    out, nE);
    } else {
        zero_out_kernel<<<1, BLOCK_P, 0, stream>>>(out);
        edge_kernel_raw<<<2048, BLOCK_P, 0, stream>>>(q, Z, ns, idx_m, is_film, r0_table,
                                                      Rij, idx_i, idx_j, out, nE);
    }
}